// Round 1
// baseline (63.362 us; speedup 1.0000x reference)
//
#include <hip/hip_runtime.h>
#include <math.h>

#define BATCH 128
#define HH 256
#define WW 256
#define HW (HH * WW)
#define HW4 (HW / 4)
#define NKPT 68

// ---------------------------------------------------------------------------
// Kernel A: per-batch similarity transform (gather 68 kpts, Kabsch via
// G^{-1/2} H^T polar form, all 3x3 algebra in double). One block per batch.
// Writes 12 floats per batch into RT: Rs[3][3] (row-major, already *sd2/sd1)
// followed by t[3].
// ---------------------------------------------------------------------------
__global__ void tform_kernel(const float* __restrict__ Offset,
                             const float* __restrict__ Posmap,
                             const float* __restrict__ meanp,
                             const int* __restrict__ uv,
                             float* __restrict__ RT) {
    __shared__ double skpt[NKPT][3];
    __shared__ double dkpt[NKPT][3];

    const int b = blockIdx.x;
    const int k = threadIdx.x;
    const float* offb = Offset + (size_t)b * 3 * HW;
    const float* dstb = Posmap + (size_t)b * 3 * HW;

    if (k < NKPT) {
        const int p = uv[k * 2 + 0] * WW + uv[k * 2 + 1];
#pragma unroll
        for (int i = 0; i < 3; i++) {
            skpt[k][i] = (double)offb[(size_t)i * HW + p] * 6.0 +
                         (double)meanp[(size_t)i * HW + p];
            dkpt[k][i] = (double)dstb[(size_t)i * HW + p];
        }
    }
    __syncthreads();
    if (threadIdx.x != 0) return;

    // sd1 / sd2: sum of distances to keypoint 33; also coordinate sums.
    double sd1 = 0.0, sd2 = 0.0;
    double ssum[3] = {0, 0, 0}, dsum[3] = {0, 0, 0};
    for (int kk = 0; kk < NKPT; kk++) {
        double ns = 0.0, nd = 0.0;
#pragma unroll
        for (int i = 0; i < 3; i++) {
            ssum[i] += skpt[kk][i];
            dsum[i] += dkpt[kk][i];
            double es = skpt[kk][i] - skpt[33][i];
            double ed = dkpt[kk][i] - dkpt[33][i];
            ns += es * es;
            nd += ed * ed;
        }
        sd1 += sqrt(ns);
        sd2 += sqrt(nd);
    }
    const double s = sd2 / sd1;
    double sbar[3], dbar[3];
#pragma unroll
    for (int i = 0; i < 3; i++) {
        sbar[i] = ssum[i] / NKPT;
        dbar[i] = dsum[i] / NKPT;
    }

    // Hm[i][j] = sum_k (s*(src_k[i]-sbar[i])) * (dst_k[j]-dbar[j])
    double Hm[3][3] = {{0, 0, 0}, {0, 0, 0}, {0, 0, 0}};
    for (int kk = 0; kk < NKPT; kk++) {
        double aa[3], bb[3];
#pragma unroll
        for (int i = 0; i < 3; i++) {
            aa[i] = (skpt[kk][i] - sbar[i]) * s;
            bb[i] = dkpt[kk][i] - dbar[i];
        }
#pragma unroll
        for (int i = 0; i < 3; i++)
#pragma unroll
            for (int j = 0; j < 3; j++) Hm[i][j] += aa[i] * bb[j];
    }

    // G = Hm^T Hm (symmetric 3x3)
    double A[3][3];
    for (int i = 0; i < 3; i++)
        for (int j = 0; j < 3; j++) {
            double acc = 0;
            for (int kk = 0; kk < 3; kk++) acc += Hm[kk][i] * Hm[kk][j];
            A[i][j] = acc;
        }

    // Cyclic Jacobi eigendecomposition: A -> diag, V columns = eigenvectors.
    double V[3][3] = {{1, 0, 0}, {0, 1, 0}, {0, 0, 1}};
    for (int sweep = 0; sweep < 50; ++sweep) {
        double off = fabs(A[0][1]) + fabs(A[0][2]) + fabs(A[1][2]);
        if (off <= 0.0) break;
        for (int p = 0; p < 2; p++)
            for (int q = p + 1; q < 3; q++) {
                double apq = A[p][q];
                if (fabs(apq) < 1e-300) continue;
                double theta = (A[q][q] - A[p][p]) / (2.0 * apq);
                double t = (theta >= 0.0 ? 1.0 : -1.0) /
                           (fabs(theta) + sqrt(theta * theta + 1.0));
                double c = 1.0 / sqrt(t * t + 1.0);
                double sn = t * c;
                A[p][p] -= t * apq;
                A[q][q] += t * apq;
                A[p][q] = 0.0;
                A[q][p] = 0.0;
                int r = 3 - p - q;  // the remaining index
                double arp = A[r][p], arq = A[r][q];
                A[r][p] = A[p][r] = c * arp - sn * arq;
                A[r][q] = A[q][r] = sn * arp + c * arq;
#pragma unroll
                for (int rr = 0; rr < 3; rr++) {
                    double vrp = V[rr][p], vrq = V[rr][q];
                    V[rr][p] = c * vrp - sn * vrq;
                    V[rr][q] = sn * vrp + c * vrq;
                }
            }
    }
    double isig[3];
#pragma unroll
    for (int i = 0; i < 3; i++) {
        double l = A[i][i];
        if (l < 1e-30) l = 1e-30;
        isig[i] = 1.0 / sqrt(l);
    }
    // Wm = V diag(1/sigma) V^T ;  R = Wm * Hm^T  ( = V U^T of the SVD )
    double Wm[3][3];
    for (int i = 0; i < 3; i++)
        for (int j = 0; j < 3; j++) {
            double acc = 0;
            for (int kk = 0; kk < 3; kk++) acc += V[i][kk] * V[j][kk] * isig[kk];
            Wm[i][j] = acc;
        }
    double R[3][3];
    for (int i = 0; i < 3; i++)
        for (int j = 0; j < 3; j++) {
            double acc = 0;
            for (int kk = 0; kk < 3; kk++) acc += Wm[i][kk] * Hm[j][kk];
            R[i][j] = acc;
        }

    float* rt = RT + b * 12;
    for (int j = 0; j < 3; j++) {
        for (int i = 0; i < 3; i++) rt[j * 3 + i] = (float)(R[j][i] * s);
        double tj = dbar[j];
        for (int i = 0; i < 3; i++) tj -= s * sbar[i] * R[j][i];
        rt[9 + j] = (float)tj;
    }
}

// ---------------------------------------------------------------------------
// Kernel B: out[b,j,h,w] = sum_i (Offset[b,i,h,w]*6 + mean[i,h,w]) * Rs[j][i]
//                          + t[j]
// float4 vectorized, planar layout, fully coalesced. 64 blocks per batch.
// ---------------------------------------------------------------------------
__global__ __launch_bounds__(256) void apply_kernel(
    const float4* __restrict__ Off, const float4* __restrict__ Mean,
    const float* __restrict__ RT, float4* __restrict__ Out) {
    const int CHUNKS = HW4 / 256;  // 64
    const int b = blockIdx.x / CHUNKS;
    const int p = (blockIdx.x % CHUNKS) * 256 + threadIdx.x;

    const float* rt = RT + b * 12;
    const float r00 = rt[0], r01 = rt[1], r02 = rt[2];
    const float r10 = rt[3], r11 = rt[4], r12 = rt[5];
    const float r20 = rt[6], r21 = rt[7], r22 = rt[8];
    const float t0 = rt[9], t1 = rt[10], t2 = rt[11];

    const size_t base = (size_t)b * 3 * HW4;
    float4 o0 = Off[base + p];
    float4 o1 = Off[base + HW4 + p];
    float4 o2 = Off[base + 2 * HW4 + p];
    float4 m0 = Mean[p];
    float4 m1 = Mean[HW4 + p];
    float4 m2 = Mean[2 * HW4 + p];

    float4 y0, y1, y2;
#define APPLY(comp)                                                   \
    {                                                                 \
        float x0 = fmaf(o0.comp, 6.0f, m0.comp);                      \
        float x1 = fmaf(o1.comp, 6.0f, m1.comp);                      \
        float x2 = fmaf(o2.comp, 6.0f, m2.comp);                      \
        y0.comp = fmaf(x0, r00, fmaf(x1, r01, fmaf(x2, r02, t0)));    \
        y1.comp = fmaf(x0, r10, fmaf(x1, r11, fmaf(x2, r12, t1)));    \
        y2.comp = fmaf(x0, r20, fmaf(x1, r21, fmaf(x2, r22, t2)));    \
    }
    APPLY(x)
    APPLY(y)
    APPLY(z)
    APPLY(w)
#undef APPLY

    Out[base + p] = y0;
    Out[base + HW4 + p] = y1;
    Out[base + 2 * HW4 + p] = y2;
}

extern "C" void kernel_launch(void* const* d_in, const int* in_sizes, int n_in,
                              void* d_out, int out_size, void* d_ws,
                              size_t ws_size, hipStream_t stream) {
    const float* Offset = (const float*)d_in[0];
    const float* Posmap = (const float*)d_in[1];
    const float* meanp = (const float*)d_in[2];
    const int* uv = (const int*)d_in[3];
    float* out = (float*)d_out;
    float* RT = (float*)d_ws;  // 128 * 12 floats

    tform_kernel<<<BATCH, 128, 0, stream>>>(Offset, Posmap, meanp, uv, RT);
    apply_kernel<<<BATCH * (HW4 / 256), 256, 0, stream>>>(
        (const float4*)Offset, (const float4*)meanp, RT, (float4*)out);
}

// Round 2
// 44.002 us; speedup vs baseline: 1.4400x; 1.4400x over previous
//
#include <hip/hip_runtime.h>
#include <math.h>

#define BATCH 128
#define HH 256
#define WW 256
#define HW (HH * WW)
#define HW4 (HW / 4)
#define NKPT 68

__device__ inline double wave_sum64(double v) {
#pragma unroll
    for (int off = 32; off > 0; off >>= 1) v += __shfl_xor(v, off);
    return v;
}

// ---------------------------------------------------------------------------
// Kernel A: per-batch similarity transform. One wave (64 lanes) per batch.
// Lanes 0..63 own keypoint `lane`; lanes 0..3 additionally own `lane+64`.
// All 17 reductions (sd1, sd2, ssum[3], dsum[3], Hm[9]) are butterfly
// shuffle reductions; only the 3x3 Jacobi eigen-solve is serial on lane 0.
// Writes 12 floats per batch into RT: Rs[3][3] row-major (already *sd2/sd1)
// followed by t[3].
// ---------------------------------------------------------------------------
__global__ __launch_bounds__(64) void tform_kernel(
    const float* __restrict__ Offset, const float* __restrict__ Posmap,
    const float* __restrict__ meanp, const int* __restrict__ uv,
    float* __restrict__ RT) {
    const int b = blockIdx.x;
    const int lane = threadIdx.x;
    const float* offb = Offset + (size_t)b * 3 * HW;
    const float* dstb = Posmap + (size_t)b * 3 * HW;

    const bool has1 = lane < (NKPT - 64);  // lanes 0..3 carry a 2nd keypoint

    // Gather keypoint(s) into registers (double).
    double s0[3], d0[3], s1[3] = {0, 0, 0}, d1[3] = {0, 0, 0};
    {
        const int p0 = uv[lane * 2 + 0] * WW + uv[lane * 2 + 1];
#pragma unroll
        for (int i = 0; i < 3; i++) {
            s0[i] = (double)offb[(size_t)i * HW + p0] * 6.0 +
                    (double)meanp[(size_t)i * HW + p0];
            d0[i] = (double)dstb[(size_t)i * HW + p0];
        }
        if (has1) {
            const int k1 = lane + 64;
            const int p1 = uv[k1 * 2 + 0] * WW + uv[k1 * 2 + 1];
#pragma unroll
            for (int i = 0; i < 3; i++) {
                s1[i] = (double)offb[(size_t)i * HW + p1] * 6.0 +
                        (double)meanp[(size_t)i * HW + p1];
                d1[i] = (double)dstb[(size_t)i * HW + p1];
            }
        }
    }

    // Broadcast keypoint 33 (owned by lane 33).
    double s33[3], d33[3];
#pragma unroll
    for (int i = 0; i < 3; i++) {
        s33[i] = __shfl(s0[i], 33);
        d33[i] = __shfl(d0[i], 33);
    }

    // Per-lane partials for sd1, sd2 and coordinate sums.
    double ns0 = 0, nd0 = 0, ns1 = 0, nd1 = 0;
    double ssum[3], dsum[3];
#pragma unroll
    for (int i = 0; i < 3; i++) {
        double es = s0[i] - s33[i], ed = d0[i] - d33[i];
        ns0 += es * es;
        nd0 += ed * ed;
        es = s1[i] - s33[i];
        ed = d1[i] - d33[i];
        ns1 += es * es;
        nd1 += ed * ed;
        ssum[i] = s0[i] + s1[i];
        dsum[i] = d0[i] + d1[i];
    }
    double sd1p = sqrt(ns0) + (has1 ? sqrt(ns1) : 0.0);
    double sd2p = sqrt(nd0) + (has1 ? sqrt(nd1) : 0.0);

    const double sd1 = wave_sum64(sd1p);
    const double sd2 = wave_sum64(sd2p);
#pragma unroll
    for (int i = 0; i < 3; i++) {
        ssum[i] = wave_sum64(ssum[i]);
        dsum[i] = wave_sum64(dsum[i]);
    }

    const double s = sd2 / sd1;
    double sbar[3], dbar[3];
#pragma unroll
    for (int i = 0; i < 3; i++) {
        sbar[i] = ssum[i] / NKPT;
        dbar[i] = dsum[i] / NKPT;
    }

    // Hm[i][j] = sum_k (s*(src_k[i]-sbar[i])) * (dst_k[j]-dbar[j])
    double Hm[3][3];
    {
        double aa0[3], bb0[3], aa1[3], bb1[3];
#pragma unroll
        for (int i = 0; i < 3; i++) {
            aa0[i] = (s0[i] - sbar[i]) * s;
            bb0[i] = d0[i] - dbar[i];
            aa1[i] = has1 ? (s1[i] - sbar[i]) * s : 0.0;
            bb1[i] = has1 ? (d1[i] - dbar[i]) : 0.0;
        }
#pragma unroll
        for (int i = 0; i < 3; i++)
#pragma unroll
            for (int j = 0; j < 3; j++)
                Hm[i][j] = wave_sum64(aa0[i] * bb0[j] + aa1[i] * bb1[j]);
    }

    if (lane != 0) return;

    // G = Hm^T Hm (symmetric 3x3)
    double A[3][3];
    for (int i = 0; i < 3; i++)
        for (int j = 0; j < 3; j++) {
            double acc = 0;
            for (int kk = 0; kk < 3; kk++) acc += Hm[kk][i] * Hm[kk][j];
            A[i][j] = acc;
        }

    // Cyclic Jacobi eigendecomposition: A -> diag, V columns = eigenvectors.
    double V[3][3] = {{1, 0, 0}, {0, 1, 0}, {0, 0, 1}};
    for (int sweep = 0; sweep < 12; ++sweep) {
        double off = fabs(A[0][1]) + fabs(A[0][2]) + fabs(A[1][2]);
        double diag = fabs(A[0][0]) + fabs(A[1][1]) + fabs(A[2][2]);
        if (off <= diag * 1e-15) break;
        for (int p = 0; p < 2; p++)
            for (int q = p + 1; q < 3; q++) {
                double apq = A[p][q];
                if (fabs(apq) < 1e-300) continue;
                double theta = (A[q][q] - A[p][p]) / (2.0 * apq);
                double t = (theta >= 0.0 ? 1.0 : -1.0) /
                           (fabs(theta) + sqrt(theta * theta + 1.0));
                double c = 1.0 / sqrt(t * t + 1.0);
                double sn = t * c;
                A[p][p] -= t * apq;
                A[q][q] += t * apq;
                A[p][q] = 0.0;
                A[q][p] = 0.0;
                int r = 3 - p - q;
                double arp = A[r][p], arq = A[r][q];
                A[r][p] = A[p][r] = c * arp - sn * arq;
                A[r][q] = A[q][r] = sn * arp + c * arq;
#pragma unroll
                for (int rr = 0; rr < 3; rr++) {
                    double vrp = V[rr][p], vrq = V[rr][q];
                    V[rr][p] = c * vrp - sn * vrq;
                    V[rr][q] = sn * vrp + c * vrq;
                }
            }
    }
    double isig[3];
#pragma unroll
    for (int i = 0; i < 3; i++) {
        double l = A[i][i];
        if (l < 1e-30) l = 1e-30;
        isig[i] = 1.0 / sqrt(l);
    }
    // Wm = V diag(1/sigma) V^T ;  R = Wm * Hm^T  ( = V U^T of the SVD )
    double Wm[3][3];
    for (int i = 0; i < 3; i++)
        for (int j = 0; j < 3; j++) {
            double acc = 0;
            for (int kk = 0; kk < 3; kk++) acc += V[i][kk] * V[j][kk] * isig[kk];
            Wm[i][j] = acc;
        }
    double R[3][3];
    for (int i = 0; i < 3; i++)
        for (int j = 0; j < 3; j++) {
            double acc = 0;
            for (int kk = 0; kk < 3; kk++) acc += Wm[i][kk] * Hm[j][kk];
            R[i][j] = acc;
        }

    float* rt = RT + b * 12;
    for (int j = 0; j < 3; j++) {
        for (int i = 0; i < 3; i++) rt[j * 3 + i] = (float)(R[j][i] * s);
        double tj = dbar[j];
        for (int i = 0; i < 3; i++) tj -= s * sbar[i] * R[j][i];
        rt[9 + j] = (float)tj;
    }
}

// ---------------------------------------------------------------------------
// Kernel B: out[b,j,h,w] = sum_i (Offset[b,i,h,w]*6 + mean[i,h,w]) * Rs[j][i]
//                          + t[j]
// float4 vectorized, planar layout, fully coalesced. 64 blocks per batch.
// ---------------------------------------------------------------------------
__global__ __launch_bounds__(256) void apply_kernel(
    const float4* __restrict__ Off, const float4* __restrict__ Mean,
    const float* __restrict__ RT, float4* __restrict__ Out) {
    const int CHUNKS = HW4 / 256;  // 64
    const int b = blockIdx.x / CHUNKS;
    const int p = (blockIdx.x % CHUNKS) * 256 + threadIdx.x;

    const float* rt = RT + b * 12;
    const float r00 = rt[0], r01 = rt[1], r02 = rt[2];
    const float r10 = rt[3], r11 = rt[4], r12 = rt[5];
    const float r20 = rt[6], r21 = rt[7], r22 = rt[8];
    const float t0 = rt[9], t1 = rt[10], t2 = rt[11];

    const size_t base = (size_t)b * 3 * HW4;
    float4 o0 = Off[base + p];
    float4 o1 = Off[base + HW4 + p];
    float4 o2 = Off[base + 2 * HW4 + p];
    float4 m0 = Mean[p];
    float4 m1 = Mean[HW4 + p];
    float4 m2 = Mean[2 * HW4 + p];

    float4 y0, y1, y2;
#define APPLY(comp)                                                   \
    {                                                                 \
        float x0 = fmaf(o0.comp, 6.0f, m0.comp);                      \
        float x1 = fmaf(o1.comp, 6.0f, m1.comp);                      \
        float x2 = fmaf(o2.comp, 6.0f, m2.comp);                      \
        y0.comp = fmaf(x0, r00, fmaf(x1, r01, fmaf(x2, r02, t0)));    \
        y1.comp = fmaf(x0, r10, fmaf(x1, r11, fmaf(x2, r12, t1)));    \
        y2.comp = fmaf(x0, r20, fmaf(x1, r21, fmaf(x2, r22, t2)));    \
    }
    APPLY(x)
    APPLY(y)
    APPLY(z)
    APPLY(w)
#undef APPLY

    Out[base + p] = y0;
    Out[base + HW4 + p] = y1;
    Out[base + 2 * HW4 + p] = y2;
}

extern "C" void kernel_launch(void* const* d_in, const int* in_sizes, int n_in,
                              void* d_out, int out_size, void* d_ws,
                              size_t ws_size, hipStream_t stream) {
    const float* Offset = (const float*)d_in[0];
    const float* Posmap = (const float*)d_in[1];
    const float* meanp = (const float*)d_in[2];
    const int* uv = (const int*)d_in[3];
    float* out = (float*)d_out;
    float* RT = (float*)d_ws;  // 128 * 12 floats

    tform_kernel<<<BATCH, 64, 0, stream>>>(Offset, Posmap, meanp, uv, RT);
    apply_kernel<<<BATCH * (HW4 / 256), 256, 0, stream>>>(
        (const float4*)Offset, (const float4*)meanp, RT, (float4*)out);
}